// Round 8
// baseline (112.894 us; speedup 1.0000x reference)
//
#include <hip/hip_runtime.h>

// Chamfer distance via bf16 MFMA with split-bf16 (hi+lo) distance packing.
// B=4, N=M=8192, f32 in/out. out = [dist1 (B*N) | dist2 (B*M)].
//
// d[i][j] = |q_i|^2 + |r_j|^2 - 2 q_i.r_j computed entirely inside
// v_mfma_f32_32x32x16_bf16 via K=16 slot packing (see chamfer_prep).
//
// R7 = R5's proven numerics (nested-fminf min3 fold; NO inline-asm min on
// MFMA outputs — that was the R3/R4 hazard bug; separate out-init) +
//   - LDS B-staging: global_load_lds double-buffer, one barrier per buffer.
//     Cuts L2 B-traffic 4x (each tile fetched once per block, not per wave).
//   - QPW=2: two A-fragments per wave amortize each B ds_read over 2 MFMAs.
//   - LDS union: staging buffers (16KB) and reduce scratch (33KB) share one
//     allocation (33KB total) -> 4 blocks/CU preserved.

typedef __bf16 bf16_t;
typedef __bf16 bf16x8 __attribute__((ext_vector_type(8)));
typedef float  f32x16 __attribute__((ext_vector_type(16)));

#define NPTS    8192
#define NB      4
#define NSETPTS (NB * NPTS)          // 32768 points per set
#define TPB     256
#define WAVES   4
#define QPW     2                    // q-tiles (of 32 rows) per wave
#define QC      (WAVES * QPW * 32)   // 256 query rows per block
#define QPANELS (NPTS / QC)          // 32
#define SEGR    4                    // ref-dim split
#define RC      (NPTS / SEGR)        // 2048 refs per block sweep
#define RT      (RC / 32)            // 64 r-tiles per sweep
#define BUFTILES 8                   // tiles per LDS buffer
#define BUFBF   (BUFTILES * 32 * 16) // 4096 bf16 = 8 KiB per buffer
#define NBUF    (RT / BUFTILES)      // 8 buffers per sweep

__global__ void chamfer_init_out(unsigned int* __restrict__ out, int n) {
    int i = blockIdx.x * blockDim.x + threadIdx.x;
    if (i < n) out[i] = 0x7F800000u;  // +inf bits
}

__device__ __forceinline__ void gload16(const bf16_t* g, bf16_t* l) {
    __builtin_amdgcn_global_load_lds(
        (const __attribute__((address_space(1))) void*)g,
        (__attribute__((address_space(3))) void*)l, 16, 0, 0);
}

__device__ __forceinline__ void split2(float v, bf16_t& h, bf16_t& l) {
    h = (bf16_t)v;
    l = (bf16_t)(v - (float)h);
}

// Per-point K=16 slot vectors (A-side and B-side), stored pre-permuted so a
// lane's fragment load is one 16B load: stored[j] = logical[perm[j]],
// perm = {0,1,2,3, 8,9,10,11, 4,5,6,7, 12,13,14,15}.
// Slots: k0-2 (-2q)_hi*r_hi | k3-5 (-2q)_lo*r_hi | k6-8 (-2q)_hi*r_lo |
//        k9-10 |q|^2 hi/lo * 1 | k11-12 1 * |r|^2 hi/lo | k13-15 zero.
__global__ void chamfer_prep(const float* __restrict__ xyz1,
                             const float* __restrict__ xyz2,
                             bf16_t* __restrict__ a16,
                             bf16_t* __restrict__ b16) {
    int i = blockIdx.x * blockDim.x + threadIdx.x;   // 0..2*NSETPTS-1
    const float* src = (i >= NSETPTS) ? xyz2 : xyz1;
    int p = i & (NSETPTS - 1);
    float x = src[3 * p], y = src[3 * p + 1], z = src[3 * p + 2];
    float sq = x * x + y * y + z * z;

    bf16_t m2xh, m2xl, m2yh, m2yl, m2zh, m2zl;
    split2(-2.f * x, m2xh, m2xl);
    split2(-2.f * y, m2yh, m2yl);
    split2(-2.f * z, m2zh, m2zl);
    bf16_t xh, xl, yh, yl, zh, zl;
    split2(x, xh, xl); split2(y, yh, yl); split2(z, zh, zl);
    bf16_t sqh, sql;
    split2(sq, sqh, sql);
    bf16_t one = (bf16_t)1.0f, zero = (bf16_t)0.0f;

    bf16_t A[16]  = { m2xh, m2yh, m2zh,  m2xl, m2yl, m2zl,
                      m2xh, m2yh, m2zh,  sqh, sql, one, one, zero, zero, zero };
    bf16_t Bv[16] = { xh, yh, zh,  xh, yh, zh,  xl, yl, zl,
                      one, one, sqh, sql, zero, zero, zero };

    const int perm[16] = {0,1,2,3, 8,9,10,11, 4,5,6,7, 12,13,14,15};
    bf16_t* ao = a16 + (size_t)i * 16;
    bf16_t* bo = b16 + (size_t)i * 16;
#pragma unroll
    for (int j = 0; j < 16; ++j) { ao[j] = A[perm[j]]; bo[j] = Bv[perm[j]]; }
}

__global__ __launch_bounds__(TPB, 4) void chamfer_main(
    const bf16_t* __restrict__ a16,
    const bf16_t* __restrict__ b16,
    unsigned int* __restrict__ out)
{
    // Union: staging buffers (2 x 8KB) during the loop, reduce scratch after.
    __shared__ __align__(16) unsigned char smem[WAVES * QPW * 32 * 33 * 4];
    bf16_t* sbuf = (bf16_t*)smem;                       // [2][BUFBF]
    float (*red)[QPW][32][33] = (float (*)[QPW][32][33])smem;

    int bid = blockIdx.x;
    int s   = bid & (SEGR - 1);    bid >>= 2;   // reference segment
    int qp  = bid & (QPANELS - 1); bid >>= 5;   // q-panel
    int b   = bid & 3;             bid >>= 2;   // batch
    int dir = bid;                              // 0: q=xyz1,r=xyz2 ; 1: swapped

    int wave = threadIdx.x >> 6;
    int lane = threadIdx.x & 63;
    int col  = lane & 31;                    // A-row / B-col index
    int h    = lane >> 5;                    // k sub-group
    int fragoff = col * 16 + h * 8;          // bf16 elems within a 32-pt tile

    const bf16_t* ap = a16 + ((size_t)dir * NB + b) * NPTS * 16;
    const bf16_t* bp = b16 + ((size_t)(1 - dir) * NB + b) * NPTS * 16;
    const bf16_t* gB = bp + (size_t)(s * RC) * 16;

    int qbase = qp * QC + wave * (QPW * 32);
    bf16x8 af0 = *((const bf16x8*)(ap + (size_t)(qbase + col) * 16) + h);
    bf16x8 af1 = *((const bf16x8*)(ap + (size_t)(qbase + 32 + col) * 16) + h);

    f32x16 rm0, rm1, zacc;
#pragma unroll
    for (int g = 0; g < 16; ++g) { rm0[g] = INFINITY; rm1[g] = INFINITY; zacc[g] = 0.f; }

    // Prologue: stage buffer 0 (each wave: 2 x 1KiB linear rounds).
    gload16(gB + wave * 512 + lane * 8,       sbuf + wave * 512);
    gload16(gB + (4 + wave) * 512 + lane * 8, sbuf + (4 + wave) * 512);

    for (int bi = 0; bi < NBUF; ++bi) {
        int cur = bi & 1;
        __syncthreads();   // compiler drains vmcnt+lgkmcnt before s_barrier:
                           // sb[cur] staged data visible to all waves, and all
                           // waves are done reading sb[cur^1] (prev iter).
        if (bi + 1 < NBUF) {
            const bf16_t* gn = gB + (size_t)(bi + 1) * BUFBF;
            bf16_t* dn = sbuf + (cur ^ 1) * BUFBF;
            gload16(gn + wave * 512 + lane * 8,       dn + wave * 512);
            gload16(gn + (4 + wave) * 512 + lane * 8, dn + (4 + wave) * 512);
        }
        const bf16_t* sc = sbuf + cur * BUFBF;
#pragma unroll
        for (int pg = 0; pg < BUFTILES / 2; ++pg) {
            bf16x8 c0 = *(const bf16x8*)(sc + (2 * pg + 0) * 512 + fragoff);
            bf16x8 c1 = *(const bf16x8*)(sc + (2 * pg + 1) * 512 + fragoff);

            f32x16 a0 = __builtin_amdgcn_mfma_f32_32x32x16_bf16(af0, c0, zacc, 0, 0, 0);
            f32x16 a1 = __builtin_amdgcn_mfma_f32_32x32x16_bf16(af0, c1, zacc, 0, 0, 0);
#pragma unroll
            for (int g = 0; g < 16; ++g)
                rm0[g] = fminf(fminf(a0[g], a1[g]), rm0[g]);   // min3-fusable

            f32x16 a2 = __builtin_amdgcn_mfma_f32_32x32x16_bf16(af1, c0, zacc, 0, 0, 0);
            f32x16 a3 = __builtin_amdgcn_mfma_f32_32x32x16_bf16(af1, c1, zacc, 0, 0, 0);
#pragma unroll
            for (int g = 0; g < 16; ++g)
                rm1[g] = fminf(fminf(a2[g], a3[g]), rm1[g]);
        }
    }

    __syncthreads();   // all waves done with sbuf; red may now alias it

    // Scatter running row-mins: D row = (g&3) + 8*(g>>2) + 4*h (verified layout).
#pragma unroll
    for (int g = 0; g < 16; ++g) {
        int row = (g & 3) + 8 * (g >> 2) + 4 * h;
        red[wave][0][row][col] = rm0[g];
        red[wave][1][row][col] = rm1[g];
    }
    __syncthreads();

    // One thread per block q-row: reduce 32 col-slots, clamp, publish.
    {
        int w   = threadIdx.x >> 6;
        int rem = threadIdx.x & 63;
        int qt  = rem >> 5;
        int r   = rem & 31;
        const float* rp = &red[w][qt][r][0];
        float v0 = rp[0], v1 = rp[1], v2 = rp[2], v3 = rp[3];
#pragma unroll
        for (int c = 4; c < 32; c += 4) {
            v0 = fminf(v0, rp[c + 0]);
            v1 = fminf(v1, rp[c + 1]);
            v2 = fminf(v2, rp[c + 2]);
            v3 = fminf(v3, rp[c + 3]);
        }
        float v = fmaxf(fminf(fminf(v0, v1), fminf(v2, v3)), 0.f);
        unsigned idx = (unsigned)(dir * NSETPTS + b * NPTS + qp * QC + threadIdx.x);
        atomicMin(&out[idx], __float_as_uint(v));
    }
}

extern "C" void kernel_launch(void* const* d_in, const int* in_sizes, int n_in,
                              void* d_out, int out_size, void* d_ws, size_t ws_size,
                              hipStream_t stream) {
    const float* xyz1 = (const float*)d_in[0];
    const float* xyz2 = (const float*)d_in[1];
    unsigned int* out = (unsigned int*)d_out;

    bf16_t* a16 = (bf16_t*)d_ws;                          // 2 MB
    bf16_t* b16 = a16 + (size_t)2 * NSETPTS * 16;         // +2 MB

    hipLaunchKernelGGL(chamfer_init_out,
                       dim3((out_size + TPB - 1) / TPB), dim3(TPB), 0, stream,
                       out, out_size);

    hipLaunchKernelGGL(chamfer_prep,
                       dim3(2 * NSETPTS / TPB), dim3(TPB), 0, stream,
                       xyz1, xyz2, a16, b16);

    // 2 dirs x 4 batches x 32 q-panels x 4 ref-segments = 1024 blocks
    hipLaunchKernelGGL(chamfer_main,
                       dim3(2 * NB * QPANELS * SEGR), dim3(TPB), 0, stream,
                       a16, b16, out);
}

// Round 9
// 84.526 us; speedup vs baseline: 1.3356x; 1.3356x over previous
//
#include <hip/hip_runtime.h>

// Chamfer distance via bf16 MFMA with split-bf16 (hi+lo) distance packing.
// B=4, N=M=8192, f32 in/out. out = [dist1 (B*N) | dist2 (B*M)].
//
// d[i][j] = |q_i|^2 + |r_j|^2 - 2 q_i.r_j computed entirely inside
// v_mfma_f32_32x32x16_bf16 via K=16 slot packing (see chamfer_prep).
//
// R9 structure:
//  - whole-segment B staging: 32KB via global_load_lds, ONE barrier
//    (R8's barrier-per-8-tiles drain was the latency bug: MfmaUtil 10%).
//  - QPW=4: one 1KB B-fragment read feeds 4 MFMAs (per-CU LDS traffic 512KB).
//  - B-side global layout pre-swizzled (slot s -> s ^ (p&7), bijective) so the
//    linear global_load_lds + swizzled ds_read is 2-way-conflict-free
//    (R8 counter: 1.05M conflicts from the 4-way 32B-stride pattern).
//  - reduce scratch unioned onto the B buffer after compute (33KB, 4 blk/CU).
//  - proven pieces kept: nested-fminf min3 fold (NO inline-asm min on MFMA
//    outputs - the R3/R4 hazard bug), separate out-init, LDS row-reduce.

typedef __bf16 bf16_t;
typedef __bf16 bf16x8 __attribute__((ext_vector_type(8)));
typedef float  f32x16 __attribute__((ext_vector_type(16)));

#define NPTS    8192
#define NB      4
#define NSETPTS (NB * NPTS)          // 32768 points per set
#define TPB     256
#define WAVES   4
#define QPW     4                    // q-tiles (of 32 rows) per wave
#define QC      (WAVES * QPW * 32)   // 512 query rows per block
#define QPANELS (NPTS / QC)          // 16
#define SEGR    8                    // ref-dim split
#define RC      (NPTS / SEGR)        // 1024 refs per block sweep
#define RT      (RC / 32)            // 32 r-tiles per sweep
#define NSLOT   (RC * 2)             // 16B slots in the B segment (2048)

__global__ void chamfer_init_out(unsigned int* __restrict__ out, int n) {
    int i = blockIdx.x * blockDim.x + threadIdx.x;
    if (i < n) out[i] = 0x7F800000u;  // +inf bits
}

__device__ __forceinline__ void gload16(const bf16_t* g, bf16_t* l) {
    __builtin_amdgcn_global_load_lds(
        (const __attribute__((address_space(1))) void*)g,
        (__attribute__((address_space(3))) void*)l, 16, 0, 0);
}

__device__ __forceinline__ void split2(float v, bf16_t& h, bf16_t& l) {
    h = (bf16_t)v;
    l = (bf16_t)(v - (float)h);
}

// Per-point K=16 slot vectors. stored[j] = logical[perm[j]],
// perm = {0,1,2,3, 8,9,10,11, 4,5,6,7, 12,13,14,15} (fragment halves).
// Slots: k0-2 (-2q)_hi*r_hi | k3-5 (-2q)_lo*r_hi | k6-8 (-2q)_hi*r_lo |
//        k9-10 |q|^2 hi/lo * 1 | k11-12 1 * |r|^2 hi/lo | k13-15 zero.
// A-side: linear (read per-lane from global).  B-side: within each 32-point
// tile, 16B-slot s (= 2p+h) is stored at s' = s ^ (p&7) — bank-spreading
// swizzle; main's ds_read applies the same XOR.
__global__ void chamfer_prep(const float* __restrict__ xyz1,
                             const float* __restrict__ xyz2,
                             bf16_t* __restrict__ a16,
                             bf16_t* __restrict__ b16) {
    int i = blockIdx.x * blockDim.x + threadIdx.x;   // 0..2*NSETPTS-1
    const float* src = (i >= NSETPTS) ? xyz2 : xyz1;
    int p32 = i & (NSETPTS - 1);
    float x = src[3 * p32], y = src[3 * p32 + 1], z = src[3 * p32 + 2];
    float sq = x * x + y * y + z * z;

    bf16_t m2xh, m2xl, m2yh, m2yl, m2zh, m2zl;
    split2(-2.f * x, m2xh, m2xl);
    split2(-2.f * y, m2yh, m2yl);
    split2(-2.f * z, m2zh, m2zl);
    bf16_t xh, xl, yh, yl, zh, zl;
    split2(x, xh, xl); split2(y, yh, yl); split2(z, zh, zl);
    bf16_t sqh, sql;
    split2(sq, sqh, sql);
    bf16_t one = (bf16_t)1.0f, zero = (bf16_t)0.0f;

    bf16_t A[16]  = { m2xh, m2yh, m2zh,  m2xl, m2yl, m2zl,
                      m2xh, m2yh, m2zh,  sqh, sql, one, one, zero, zero, zero };
    bf16_t Bv[16] = { xh, yh, zh,  xh, yh, zh,  xl, yl, zl,
                      one, one, sqh, sql, zero, zero, zero };

    const int perm[16] = {0,1,2,3, 8,9,10,11, 4,5,6,7, 12,13,14,15};

    // A: linear
    bf16_t* ao = a16 + (size_t)i * 16;
#pragma unroll
    for (int j = 0; j < 16; ++j) ao[j] = A[perm[j]];

    // B: tile-local slot swizzle
    int p = i & 31;
    size_t tb = (size_t)(i & ~31) * 16;          // tile base (bf16 elems)
    int s0 = (2 * p)     ^ (p & 7);
    int s1 = (2 * p + 1) ^ (p & 7);
    bf16_t* bo0 = b16 + tb + (size_t)s0 * 8;
    bf16_t* bo1 = b16 + tb + (size_t)s1 * 8;
#pragma unroll
    for (int j = 0; j < 8; ++j) bo0[j] = Bv[perm[j]];
#pragma unroll
    for (int j = 0; j < 8; ++j) bo1[j] = Bv[perm[j + 8]];
}

__global__ __launch_bounds__(TPB) void chamfer_main(
    const bf16_t* __restrict__ a16,
    const bf16_t* __restrict__ b16,
    unsigned int* __restrict__ out)
{
    // Union: B segment (32KB) during compute; reduce scratch (16.9KB) after.
    __shared__ __align__(16) unsigned char smem[NSLOT * 16];
    bf16_t* sbuf = (bf16_t*)smem;
    float (*red)[32][33] = (float (*)[32][33])smem;   // [WAVES][32][33]

    int bid = blockIdx.x;
    int s   = bid & (SEGR - 1);    bid >>= 3;   // reference segment
    int qp  = bid & (QPANELS - 1); bid >>= 4;   // q-panel
    int b   = bid & 3;             bid >>= 2;   // batch
    int dir = bid;                              // 0: q=xyz1,r=xyz2 ; 1: swapped

    int wave = threadIdx.x >> 6;
    int lane = threadIdx.x & 63;
    int col  = lane & 31;
    int h    = lane >> 5;

    const bf16_t* ap = a16 + ((size_t)dir * NB + b) * NPTS * 16;
    const bf16_t* bp = b16 + ((size_t)(1 - dir) * NB + b) * NPTS * 16;
    const bf16_t* gB = bp + (size_t)(s * RC) * 16;

    // Stage the whole 32KB B segment: 8 rounds x 256 threads x 16B.
    // LDS dest = wave-uniform base + lane*16 (linear; swizzle is pre-baked
    // into the global byte order by chamfer_prep).
#pragma unroll
    for (int c = 0; c < 8; ++c) {
        int slot = c * 256 + threadIdx.x;
        gload16(gB + (size_t)slot * 8, sbuf + (size_t)slot * 8);
    }

    // A fragments (direct global, once per sweep).
    int qbase = qp * QC + wave * (QPW * 32);
    bf16x8 af0 = *((const bf16x8*)(ap + (size_t)(qbase +  0 + col) * 16) + h);
    bf16x8 af1 = *((const bf16x8*)(ap + (size_t)(qbase + 32 + col) * 16) + h);
    bf16x8 af2 = *((const bf16x8*)(ap + (size_t)(qbase + 64 + col) * 16) + h);
    bf16x8 af3 = *((const bf16x8*)(ap + (size_t)(qbase + 96 + col) * 16) + h);

    f32x16 rm0, rm1, rm2, rm3, zacc;
#pragma unroll
    for (int g = 0; g < 16; ++g) {
        rm0[g] = INFINITY; rm1[g] = INFINITY;
        rm2[g] = INFINITY; rm3[g] = INFINITY; zacc[g] = 0.f;
    }

    __syncthreads();   // drains vmcnt: staged B visible to all waves

    // Per-lane swizzled fragment offset within a tile (bf16 elems).
    int swz = ((2 * col + h) ^ (col & 7)) * 8;
    const bf16_t* sl = sbuf + swz;

    bf16x8 c0 = *(const bf16x8*)(sl + 0 * 512);
    bf16x8 c1 = *(const bf16x8*)(sl + 1 * 512);
    for (int t = 0; t < RT; t += 2) {
        bf16x8 p0, p1;
        if (t + 2 < RT) {
            p0 = *(const bf16x8*)(sl + (t + 2) * 512);
            p1 = *(const bf16x8*)(sl + (t + 3) * 512);
        } else { p0 = c0; p1 = c1; }

        f32x16 x0 = __builtin_amdgcn_mfma_f32_32x32x16_bf16(af0, c0, zacc, 0, 0, 0);
        f32x16 x1 = __builtin_amdgcn_mfma_f32_32x32x16_bf16(af0, c1, zacc, 0, 0, 0);
#pragma unroll
        for (int g = 0; g < 16; ++g) rm0[g] = fminf(fminf(x0[g], x1[g]), rm0[g]);

        f32x16 x2 = __builtin_amdgcn_mfma_f32_32x32x16_bf16(af1, c0, zacc, 0, 0, 0);
        f32x16 x3 = __builtin_amdgcn_mfma_f32_32x32x16_bf16(af1, c1, zacc, 0, 0, 0);
#pragma unroll
        for (int g = 0; g < 16; ++g) rm1[g] = fminf(fminf(x2[g], x3[g]), rm1[g]);

        f32x16 x4 = __builtin_amdgcn_mfma_f32_32x32x16_bf16(af2, c0, zacc, 0, 0, 0);
        f32x16 x5 = __builtin_amdgcn_mfma_f32_32x32x16_bf16(af2, c1, zacc, 0, 0, 0);
#pragma unroll
        for (int g = 0; g < 16; ++g) rm2[g] = fminf(fminf(x4[g], x5[g]), rm2[g]);

        f32x16 x6 = __builtin_amdgcn_mfma_f32_32x32x16_bf16(af3, c0, zacc, 0, 0, 0);
        f32x16 x7 = __builtin_amdgcn_mfma_f32_32x32x16_bf16(af3, c1, zacc, 0, 0, 0);
#pragma unroll
        for (int g = 0; g < 16; ++g) rm3[g] = fminf(fminf(x6[g], x7[g]), rm3[g]);

        c0 = p0; c1 = p1;
    }

    __syncthreads();   // B consumed; red may alias sbuf
    int outbase = dir * NSETPTS + b * NPTS + qp * QC;

    // 4 sequential reduce passes (one per q-tile), proven LDS-red pattern.
    // D row = (g&3) + 8*(g>>2) + 4*h (verified layout).
#define RED_PASS(QT, RM)                                                      \
    {                                                                         \
        _Pragma("unroll")                                                     \
        for (int g = 0; g < 16; ++g) {                                        \
            int row = (g & 3) + 8 * (g >> 2) + 4 * h;                         \
            red[wave][row][col] = RM[g];                                      \
        }                                                                     \
        __syncthreads();                                                      \
        if (threadIdx.x < 128) {                                              \
            int w = threadIdx.x >> 5, r = threadIdx.x & 31;                   \
            const float* rp = &red[w][r][0];                                  \
            float v0 = rp[0], v1 = rp[1], v2 = rp[2], v3 = rp[3];             \
            _Pragma("unroll")                                                 \
            for (int cc = 4; cc < 32; cc += 4) {                              \
                v0 = fminf(v0, rp[cc + 0]);                                   \
                v1 = fminf(v1, rp[cc + 1]);                                   \
                v2 = fminf(v2, rp[cc + 2]);                                   \
                v3 = fminf(v3, rp[cc + 3]);                                   \
            }                                                                 \
            float v = fmaxf(fminf(fminf(v0, v1), fminf(v2, v3)), 0.f);        \
            atomicMin(&out[outbase + w * (QPW * 32) + (QT) * 32 + r],         \
                      __float_as_uint(v));                                    \
        }                                                                     \
        __syncthreads();                                                      \
    }

    RED_PASS(0, rm0)
    RED_PASS(1, rm1)
    RED_PASS(2, rm2)
    RED_PASS(3, rm3)
#undef RED_PASS
}

extern "C" void kernel_launch(void* const* d_in, const int* in_sizes, int n_in,
                              void* d_out, int out_size, void* d_ws, size_t ws_size,
                              hipStream_t stream) {
    const float* xyz1 = (const float*)d_in[0];
    const float* xyz2 = (const float*)d_in[1];
    unsigned int* out = (unsigned int*)d_out;

    bf16_t* a16 = (bf16_t*)d_ws;                          // 2 MB
    bf16_t* b16 = a16 + (size_t)2 * NSETPTS * 16;         // +2 MB

    hipLaunchKernelGGL(chamfer_init_out,
                       dim3((out_size + TPB - 1) / TPB), dim3(TPB), 0, stream,
                       out, out_size);

    hipLaunchKernelGGL(chamfer_prep,
                       dim3(2 * NSETPTS / TPB), dim3(TPB), 0, stream,
                       xyz1, xyz2, a16, b16);

    // 2 dirs x 4 batches x 16 q-panels x 8 ref-segments = 1024 blocks
    hipLaunchKernelGGL(chamfer_main,
                       dim3(2 * NB * QPANELS * SEGR), dim3(TPB), 0, stream,
                       a16, b16, out);
}

// Round 10
// 77.591 us; speedup vs baseline: 1.4550x; 1.0894x over previous
//
#include <hip/hip_runtime.h>

// Chamfer distance via bf16 MFMA with split-bf16 (hi+lo) distance packing.
// B=4, N=M=8192, f32 in/out. out = [dist1 (B*N) | dist2 (B*M)].
//
// d[i][j] = |q_i|^2 + |r_j|^2 - 2 q_i.r_j computed entirely inside
// v_mfma_f32_32x32x16_bf16 via K=16 slot packing (see chamfer_prep).
//
// R10 = R9's proven one-barrier 32KB B-staging + swizzle (cheap B path,
// 64MB total L2 traffic) x R5's proven occupancy recipe:
//   QPW=2, __launch_bounds__(256,4) -> VGPR<=128, 4 blocks/CU x 4 waves
//   = 4 waves/SIMD (R9's QPW=4 collapsed to ~2/SIMD; R8 counters showed
//   this family is latency-bound, so occupancy is the binding resource).

typedef __bf16 bf16_t;
typedef __bf16 bf16x8 __attribute__((ext_vector_type(8)));
typedef float  f32x16 __attribute__((ext_vector_type(16)));

#define NPTS    8192
#define NB      4
#define NSETPTS (NB * NPTS)          // 32768 points per set
#define TPB     256
#define WAVES   4
#define QPW     2                    // q-tiles (of 32 rows) per wave
#define QC      (WAVES * QPW * 32)   // 256 query rows per block
#define QPANELS (NPTS / QC)          // 32
#define SEGR    8                    // ref-dim split
#define RC      (NPTS / SEGR)        // 1024 refs per block sweep
#define RT      (RC / 32)            // 32 r-tiles per sweep
#define NSLOT   (RC * 2)             // 16B slots in the B segment (2048)

__global__ void chamfer_init_out(unsigned int* __restrict__ out, int n) {
    int i = blockIdx.x * blockDim.x + threadIdx.x;
    if (i < n) out[i] = 0x7F800000u;  // +inf bits
}

__device__ __forceinline__ void gload16(const bf16_t* g, bf16_t* l) {
    __builtin_amdgcn_global_load_lds(
        (const __attribute__((address_space(1))) void*)g,
        (__attribute__((address_space(3))) void*)l, 16, 0, 0);
}

__device__ __forceinline__ void split2(float v, bf16_t& h, bf16_t& l) {
    h = (bf16_t)v;
    l = (bf16_t)(v - (float)h);
}

// Per-point K=16 slot vectors. stored[j] = logical[perm[j]],
// perm = {0,1,2,3, 8,9,10,11, 4,5,6,7, 12,13,14,15} (fragment halves).
// Slots: k0-2 (-2q)_hi*r_hi | k3-5 (-2q)_lo*r_hi | k6-8 (-2q)_hi*r_lo |
//        k9-10 |q|^2 hi/lo * 1 | k11-12 1 * |r|^2 hi/lo | k13-15 zero.
// A-side: linear.  B-side: within each 32-point tile, 16B-slot s (= 2p+h)
// stored at s' = s ^ (p&7) — bank-spreading swizzle (2-way = free);
// main's ds_read applies the same XOR.  (Both proven in R9: absmax 0.0156.)
__global__ void chamfer_prep(const float* __restrict__ xyz1,
                             const float* __restrict__ xyz2,
                             bf16_t* __restrict__ a16,
                             bf16_t* __restrict__ b16) {
    int i = blockIdx.x * blockDim.x + threadIdx.x;   // 0..2*NSETPTS-1
    const float* src = (i >= NSETPTS) ? xyz2 : xyz1;
    int p32 = i & (NSETPTS - 1);
    float x = src[3 * p32], y = src[3 * p32 + 1], z = src[3 * p32 + 2];
    float sq = x * x + y * y + z * z;

    bf16_t m2xh, m2xl, m2yh, m2yl, m2zh, m2zl;
    split2(-2.f * x, m2xh, m2xl);
    split2(-2.f * y, m2yh, m2yl);
    split2(-2.f * z, m2zh, m2zl);
    bf16_t xh, xl, yh, yl, zh, zl;
    split2(x, xh, xl); split2(y, yh, yl); split2(z, zh, zl);
    bf16_t sqh, sql;
    split2(sq, sqh, sql);
    bf16_t one = (bf16_t)1.0f, zero = (bf16_t)0.0f;

    bf16_t A[16]  = { m2xh, m2yh, m2zh,  m2xl, m2yl, m2zl,
                      m2xh, m2yh, m2zh,  sqh, sql, one, one, zero, zero, zero };
    bf16_t Bv[16] = { xh, yh, zh,  xh, yh, zh,  xl, yl, zl,
                      one, one, sqh, sql, zero, zero, zero };

    const int perm[16] = {0,1,2,3, 8,9,10,11, 4,5,6,7, 12,13,14,15};

    // A: linear
    bf16_t* ao = a16 + (size_t)i * 16;
#pragma unroll
    for (int j = 0; j < 16; ++j) ao[j] = A[perm[j]];

    // B: tile-local slot swizzle
    int p = i & 31;
    size_t tb = (size_t)(i & ~31) * 16;          // tile base (bf16 elems)
    int s0 = (2 * p)     ^ (p & 7);
    int s1 = (2 * p + 1) ^ (p & 7);
    bf16_t* bo0 = b16 + tb + (size_t)s0 * 8;
    bf16_t* bo1 = b16 + tb + (size_t)s1 * 8;
#pragma unroll
    for (int j = 0; j < 8; ++j) bo0[j] = Bv[perm[j]];
#pragma unroll
    for (int j = 0; j < 8; ++j) bo1[j] = Bv[perm[j + 8]];
}

__global__ __launch_bounds__(TPB, 4) void chamfer_main(
    const bf16_t* __restrict__ a16,
    const bf16_t* __restrict__ b16,
    unsigned int* __restrict__ out)
{
    // Union: B segment (32KB) during compute; reduce scratch (16.9KB) after.
    __shared__ __align__(16) unsigned char smem[NSLOT * 16];
    bf16_t* sbuf = (bf16_t*)smem;
    float (*red)[32][33] = (float (*)[32][33])smem;   // [WAVES][32][33]

    int bid = blockIdx.x;
    int s   = bid & (SEGR - 1);    bid >>= 3;   // reference segment
    int qp  = bid & (QPANELS - 1); bid >>= 5;   // q-panel
    int b   = bid & 3;             bid >>= 2;   // batch
    int dir = bid;                              // 0: q=xyz1,r=xyz2 ; 1: swapped

    int wave = threadIdx.x >> 6;
    int lane = threadIdx.x & 63;
    int col  = lane & 31;
    int h    = lane >> 5;

    const bf16_t* ap = a16 + ((size_t)dir * NB + b) * NPTS * 16;
    const bf16_t* bp = b16 + ((size_t)(1 - dir) * NB + b) * NPTS * 16;
    const bf16_t* gB = bp + (size_t)(s * RC) * 16;

    // Stage the whole 32KB B segment: 8 rounds x 256 threads x 16B.
    // (Linear LDS dest; swizzle pre-baked into global byte order by prep.)
#pragma unroll
    for (int c = 0; c < 8; ++c) {
        int slot = c * 256 + threadIdx.x;
        gload16(gB + (size_t)slot * 8, sbuf + (size_t)slot * 8);
    }

    // A fragments (direct global, once per sweep).
    int qbase = qp * QC + wave * (QPW * 32);
    bf16x8 af0 = *((const bf16x8*)(ap + (size_t)(qbase +  0 + col) * 16) + h);
    bf16x8 af1 = *((const bf16x8*)(ap + (size_t)(qbase + 32 + col) * 16) + h);

    f32x16 rm0, rm1, zacc;
#pragma unroll
    for (int g = 0; g < 16; ++g) {
        rm0[g] = INFINITY; rm1[g] = INFINITY; zacc[g] = 0.f;
    }

    __syncthreads();   // ONE barrier: drains vmcnt, staged B visible

    // Per-lane swizzled fragment offset within a tile (bf16 elems).
    int swz = ((2 * col + h) ^ (col & 7)) * 8;
    const bf16_t* sl = sbuf + swz;

    bf16x8 c0 = *(const bf16x8*)(sl + 0 * 512);
    bf16x8 c1 = *(const bf16x8*)(sl + 1 * 512);
    for (int t = 0; t < RT; t += 2) {
        bf16x8 p0, p1;
        if (t + 2 < RT) {
            p0 = *(const bf16x8*)(sl + (t + 2) * 512);
            p1 = *(const bf16x8*)(sl + (t + 3) * 512);
        } else { p0 = c0; p1 = c1; }

        f32x16 x0 = __builtin_amdgcn_mfma_f32_32x32x16_bf16(af0, c0, zacc, 0, 0, 0);
        f32x16 x1 = __builtin_amdgcn_mfma_f32_32x32x16_bf16(af0, c1, zacc, 0, 0, 0);
#pragma unroll
        for (int g = 0; g < 16; ++g) rm0[g] = fminf(fminf(x0[g], x1[g]), rm0[g]);

        f32x16 x2 = __builtin_amdgcn_mfma_f32_32x32x16_bf16(af1, c0, zacc, 0, 0, 0);
        f32x16 x3 = __builtin_amdgcn_mfma_f32_32x32x16_bf16(af1, c1, zacc, 0, 0, 0);
#pragma unroll
        for (int g = 0; g < 16; ++g) rm1[g] = fminf(fminf(x2[g], x3[g]), rm1[g]);

        c0 = p0; c1 = p1;
    }

    __syncthreads();   // B consumed; red may alias sbuf
    int outbase = dir * NSETPTS + b * NPTS + qp * QC;

    // 2 sequential reduce passes (one per q-tile), proven LDS-red pattern.
    // D row = (g&3) + 8*(g>>2) + 4*h (verified layout).
#define RED_PASS(QT, RM)                                                      \
    {                                                                         \
        _Pragma("unroll")                                                     \
        for (int g = 0; g < 16; ++g) {                                        \
            int row = (g & 3) + 8 * (g >> 2) + 4 * h;                         \
            red[wave][row][col] = RM[g];                                      \
        }                                                                     \
        __syncthreads();                                                      \
        if (threadIdx.x < 128) {                                              \
            int w = threadIdx.x >> 5, r = threadIdx.x & 31;                   \
            const float* rp = &red[w][r][0];                                  \
            float v0 = rp[0], v1 = rp[1], v2 = rp[2], v3 = rp[3];             \
            _Pragma("unroll")                                                 \
            for (int cc = 4; cc < 32; cc += 4) {                              \
                v0 = fminf(v0, rp[cc + 0]);                                   \
                v1 = fminf(v1, rp[cc + 1]);                                   \
                v2 = fminf(v2, rp[cc + 2]);                                   \
                v3 = fminf(v3, rp[cc + 3]);                                   \
            }                                                                 \
            float v = fmaxf(fminf(fminf(v0, v1), fminf(v2, v3)), 0.f);        \
            atomicMin(&out[outbase + w * (QPW * 32) + (QT) * 32 + r],         \
                      __float_as_uint(v));                                    \
        }                                                                     \
        __syncthreads();                                                      \
    }

    RED_PASS(0, rm0)
    RED_PASS(1, rm1)
#undef RED_PASS
}

extern "C" void kernel_launch(void* const* d_in, const int* in_sizes, int n_in,
                              void* d_out, int out_size, void* d_ws, size_t ws_size,
                              hipStream_t stream) {
    const float* xyz1 = (const float*)d_in[0];
    const float* xyz2 = (const float*)d_in[1];
    unsigned int* out = (unsigned int*)d_out;

    bf16_t* a16 = (bf16_t*)d_ws;                          // 2 MB
    bf16_t* b16 = a16 + (size_t)2 * NSETPTS * 16;         // +2 MB

    hipLaunchKernelGGL(chamfer_init_out,
                       dim3((out_size + TPB - 1) / TPB), dim3(TPB), 0, stream,
                       out, out_size);

    hipLaunchKernelGGL(chamfer_prep,
                       dim3(2 * NSETPTS / TPB), dim3(TPB), 0, stream,
                       xyz1, xyz2, a16, b16);

    // 2 dirs x 4 batches x 32 q-panels x 8 ref-segments = 2048 blocks
    hipLaunchKernelGGL(chamfer_main,
                       dim3(2 * NB * QPANELS * SEGR), dim3(TPB), 0, stream,
                       a16, b16, out);
}